// Round 1
// baseline (268.653 us; speedup 1.0000x reference)
//
#include <hip/hip_runtime.h>
#include <hip/hip_bf16.h>

#define NN  4
#define CIN 96
#define C1  128
#define C2  144
#define HH  128
#define WW  256

typedef short bf16x8 __attribute__((ext_vector_type(8)));
typedef float f32x4  __attribute__((ext_vector_type(4)));
typedef unsigned int u32x4 __attribute__((ext_vector_type(4)));

__device__ __forceinline__ short f2bs(float v) {
    __hip_bfloat16 b = __float2bfloat16(v);
    short s; __builtin_memcpy(&s, &b, 2); return s;
}

// async global->LDS, 16B per lane. LDS dest must be linear (base + lane*16).
__device__ __forceinline__ void gld16(const void* g, void* l) {
    __builtin_amdgcn_global_load_lds(
        (const __attribute__((address_space(1))) void*)g,
        (__attribute__((address_space(3))) void*)l, 16, 0, 0);
}

// ---------------------------------------------------------------------------
// NCHW fp32 -> NHWC bf16 transpose of feat. Block = (n,h); LDS pair-packed,
// conflict-free both phases (row stride 258 dwords). Also zeroes the 16B
// OOB-redirect scratch used by the conv kernels' global_load_lds staging.
__global__ __launch_bounds__(256) void transpose_feat(
    const float* __restrict__ feat, short* __restrict__ featT,
    short* __restrict__ zbuf)
{
    __shared__ unsigned int lds[48 * 258];        // 49.5 KB
    const int tid = threadIdx.x;
    const int h = blockIdx.x & (HH - 1);
    const int n = blockIdx.x >> 7;

    if (blockIdx.x == 0 && tid < 32) zbuf[tid] = 0;

    #pragma unroll 4
    for (int cp = 0; cp < 48; ++cp) {             // channel pairs
        float v0 = feat[(((size_t)n * CIN + 2 * cp    ) * HH + h) * WW + tid];
        float v1 = feat[(((size_t)n * CIN + 2 * cp + 1) * HH + h) * WW + tid];
        unsigned int p = (unsigned int)(unsigned short)f2bs(v0)
                       | ((unsigned int)(unsigned short)f2bs(v1) << 16);
        lds[cp * 258 + tid] = p;
    }
    __syncthreads();
    const size_t pbase = ((size_t)(n * HH + h) * WW + tid) * CIN;
    #pragma unroll
    for (int rec = 0; rec < 12; ++rec) {          // 12 x 16B per pixel record
        u32x4 v;
        #pragma unroll
        for (int k = 0; k < 4; ++k) v[k] = lds[(rec * 4 + k) * 258 + tid];
        *(u32x4*)&featT[pbase + rec * 8] = v;
    }
}

// ---------------------------------------------------------------------------
// Pack weights (co,ci,3,3) fp32 -> B-fragment-ordered bf16:
// wp[(((kci*9+tap)*nct + ct)*64 + lane)*8 + j], co=ct*16+col, ci=kci*32+quad*8+j
__global__ __launch_bounds__(256) void pack_wB(
    const float* __restrict__ w, short* __restrict__ wp,
    int cin, int nct, int total)
{
    int i = blockIdx.x * 256 + threadIdx.x;
    if (i >= total) return;
    const int j    = i & 7;
    const int col  = (i >> 3) & 15;
    const int quad = (i >> 7) & 3;
    int t = i >> 9;                               // (kci*9+tap)*nct + ct
    const int ct  = t % nct;  t /= nct;
    const int tap = t % 9;
    const int kci = t / 9;
    const int co = ct * 16 + col;
    const int ci = kci * 32 + quad * 8 + j;
    wp[i] = f2bs(w[((size_t)co * cin + ci) * 9 + tap]);
}

// ---------------------------------------------------------------------------
// conv1: featT bf16 NHWC -> hfeat bf16 NHWC. Block = (n,h), 256 thr / 4 waves,
// each wave a 64-px strip (mt=4 -> halves weight-fragment cache traffic per px).
// LDS layout [cig][row][px][8ci]: linear in staging slot (global_load_lds ok),
// conflict-free ds_read_b128 (consecutive-px within a fixed quad region).
__global__ __launch_bounds__(256, 2) void conv1_mfma(
    const short* __restrict__ featT, const short* __restrict__ w1p,
    const float* __restrict__ b1, short* __restrict__ hfeat,
    const short* __restrict__ zbuf)
{
    __shared__ __attribute__((aligned(16))) short lds[4 * 3 * 258 * 8]; // 49,536 B
    const int tid  = threadIdx.x;
    const int h    = blockIdx.x & (HH - 1);
    const int n    = blockIdx.x >> 7;
    const int lane = tid & 63, wave = tid >> 6;
    const int quad = lane >> 4, col = lane & 15;
    const int wp0  = wave * 64;

    f32x4 acc[4][8];
    #pragma unroll
    for (int mt = 0; mt < 4; ++mt)
        #pragma unroll
        for (int ct = 0; ct < 8; ++ct)
            #pragma unroll
            for (int r = 0; r < 4; ++r) acc[mt][ct][r] = 0.f;

    for (int kci = 0; kci < 3; ++kci) {
        if (kci) __syncthreads();
        // ---- stage window: slot s = (cig*3+row)*258+px, 16B each, linear ----
        for (int s = tid; s < 3 * 258 * 4; s += 256) {
            const int px  = s % 258;
            const int t   = s / 258;
            const int row = t % 3;
            const int cig = t / 3;
            const int hh = h + row - 1, gw = px - 1;
            const short* g = zbuf;
            if (hh >= 0 && hh < HH && gw >= 0 && gw < WW)
                g = &featT[(((size_t)n * HH + hh) * WW + gw) * CIN + kci * 32 + cig * 8];
            gld16(g, &lds[s * 8]);
        }
        __syncthreads();
        // ---- 9 taps of MFMA from LDS ----
        #pragma unroll
        for (int tap = 0; tap < 9; ++tap) {
            const int dh = tap / 3, dw = tap % 3;
            bf16x8 af[4];
            #pragma unroll
            for (int mt = 0; mt < 4; ++mt)
                af[mt] = *(const bf16x8*)
                    &lds[(((quad * 3 + dh) * 258) + wp0 + mt * 16 + col + dw) * 8];
            const short* bp = w1p + (((size_t)(kci * 9 + tap) * 8) << 9) + (lane << 3);
            #pragma unroll
            for (int ct = 0; ct < 8; ++ct) {
                const bf16x8 bfr = *(const bf16x8*)(bp + ((size_t)ct << 9));
                #pragma unroll
                for (int mt = 0; mt < 4; ++mt)
                    acc[mt][ct] = __builtin_amdgcn_mfma_f32_16x16x32_bf16(af[mt], bfr, acc[mt][ct], 0, 0, 0);
            }
        }
    }

    float bias[8];
    #pragma unroll
    for (int ct = 0; ct < 8; ++ct) bias[ct] = b1[ct * 16 + col];
    #pragma unroll
    for (int mt = 0; mt < 4; ++mt)
        #pragma unroll
        for (int r = 0; r < 4; ++r) {
            const int w = wp0 + mt * 16 + quad * 4 + r;
            const size_t ro = ((size_t)(n * HH + h) * WW + w) * C1;
            #pragma unroll
            for (int ct = 0; ct < 8; ++ct) {
                float a = acc[mt][ct][r] + bias[ct];
                a = a > 0.f ? a : 0.1f * a;       // LeakyReLU(0.1)
                hfeat[ro + ct * 16 + col] = f2bs(a);
            }
        }
}

// ---------------------------------------------------------------------------
// conv2 + fused bias/0.25/softmax-9/convex-upsample. mt=4 waves; flow staged
// in LDS (branch-free epilogue). K = 128 in 4 chunks.
__global__ __launch_bounds__(256, 2) void conv2_fused(
    const short* __restrict__ hfeat, const short* __restrict__ w2p,
    const float* __restrict__ b2, const float* __restrict__ flow,
    float* __restrict__ out, const short* __restrict__ zbuf)
{
    __shared__ __attribute__((aligned(16))) short lds[4 * 3 * 258 * 8]; // 49,536 B
    __shared__ float flds[2 * 3 * 264];                                  // 6,336 B
    const int tid  = threadIdx.x;
    const int h    = blockIdx.x & (HH - 1);
    const int n    = blockIdx.x >> 7;
    const int lane = tid & 63, wave = tid >> 6;
    const int quad = lane >> 4, col = lane & 15;
    const int wp0  = wave * 64;

    // stage flow rows h-1..h+1 (zero-padded) once; any later barrier orders it
    for (int i = tid; i < 2 * 3 * 258; i += 256) {
        const int px = i % 258;
        const int t  = i / 258;
        const int row = t % 3, c = t / 3;
        const int hh = h + row - 1, gw = px - 1;
        float v = 0.f;
        if (hh >= 0 && hh < HH && gw >= 0 && gw < WW)
            v = flow[(((size_t)n * 2 + c) * HH + hh) * WW + gw];
        flds[(c * 3 + row) * 264 + px] = v;
    }

    f32x4 acc[4][9];
    #pragma unroll
    for (int mt = 0; mt < 4; ++mt)
        #pragma unroll
        for (int ct = 0; ct < 9; ++ct)
            #pragma unroll
            for (int r = 0; r < 4; ++r) acc[mt][ct][r] = 0.f;

    for (int kci = 0; kci < 4; ++kci) {
        if (kci) __syncthreads();
        for (int s = tid; s < 3 * 258 * 4; s += 256) {
            const int px  = s % 258;
            const int t   = s / 258;
            const int row = t % 3;
            const int cig = t / 3;
            const int hh = h + row - 1, gw = px - 1;
            const short* g = zbuf;
            if (hh >= 0 && hh < HH && gw >= 0 && gw < WW)
                g = &hfeat[(((size_t)n * HH + hh) * WW + gw) * C1 + kci * 32 + cig * 8];
            gld16(g, &lds[s * 8]);
        }
        __syncthreads();
        #pragma unroll
        for (int tap = 0; tap < 9; ++tap) {
            const int dh = tap / 3, dw = tap % 3;
            bf16x8 af[4];
            #pragma unroll
            for (int mt = 0; mt < 4; ++mt)
                af[mt] = *(const bf16x8*)
                    &lds[(((quad * 3 + dh) * 258) + wp0 + mt * 16 + col + dw) * 8];
            const short* bp = w2p + (((size_t)(kci * 9 + tap) * 9) << 9) + (lane << 3);
            #pragma unroll
            for (int ct = 0; ct < 9; ++ct) {
                const bf16x8 bfr = *(const bf16x8*)(bp + ((size_t)ct << 9));
                #pragma unroll
                for (int mt = 0; mt < 4; ++mt)
                    acc[mt][ct] = __builtin_amdgcn_mfma_f32_16x16x32_bf16(af[mt], bfr, acc[mt][ct], 0, 0, 0);
            }
        }
    }

    const int a_ = col >> 2, b_ = col & 3;
    float bias[9];
    #pragma unroll
    for (int k = 0; k < 9; ++k) bias[k] = b2[k * 16 + col];
    const int H4 = 4 * HH, W4 = 4 * WW;

    #pragma unroll
    for (int mt = 0; mt < 4; ++mt) {
        const int w0 = wp0 + mt * 16 + quad * 4;
        float fw[2][3][6];                        // flow window w0-1 .. w0+4
        #pragma unroll
        for (int c = 0; c < 2; ++c)
            #pragma unroll
            for (int ki = 0; ki < 3; ++ki)
                #pragma unroll
                for (int j = 0; j < 6; ++j)
                    fw[c][ki][j] = flds[(c * 3 + ki) * 264 + w0 + j];
        #pragma unroll
        for (int r = 0; r < 4; ++r) {
            const int w = w0 + r;
            float v[9], mx = -1e30f;
            #pragma unroll
            for (int k = 0; k < 9; ++k) {
                v[k] = 0.25f * (acc[mt][k][r] + bias[k]);
                mx = fmaxf(mx, v[k]);
            }
            float s = 0.f;
            #pragma unroll
            for (int k = 0; k < 9; ++k) { v[k] = __expf(v[k] - mx); s += v[k]; }
            const float inv = 4.f / s;            // folds the 4*flow scale
            float o0 = 0.f, o1 = 0.f;
            #pragma unroll
            for (int ki = 0; ki < 3; ++ki)
                #pragma unroll
                for (int kj = 0; kj < 3; ++kj) {
                    const float wgt = v[ki * 3 + kj];
                    o0 += wgt * fw[0][ki][r + kj];
                    o1 += wgt * fw[1][ki][r + kj];
                }
            const size_t o = ((size_t)(n * 2) * H4 + 4 * h + a_) * W4 + 4 * w + b_;
            out[o] = o0 * inv;
            out[o + (size_t)H4 * W4] = o1 * inv;
        }
    }
}

// ---------------------------------------------------------------------------
extern "C" void kernel_launch(void* const* d_in, const int* in_sizes, int n_in,
                              void* d_out, int out_size, void* d_ws, size_t ws_size,
                              hipStream_t stream)
{
    const float* flow = (const float*)d_in[0];
    const float* feat = (const float*)d_in[1];
    const float* w1   = (const float*)d_in[2];
    const float* b1   = (const float*)d_in[3];
    const float* w2   = (const float*)d_in[4];
    const float* b2   = (const float*)d_in[5];
    float* out = (float*)d_out;

    // ws: featT 25.2 MB + hfeat 33.6 MB + w1p 0.22 MB + w2p 0.33 MB + zbuf 64B
    short* featT = (short*)d_ws;
    short* hfeat = featT + (size_t)NN * HH * WW * CIN;   // 12,582,912
    short* w1p   = hfeat + (size_t)NN * HH * WW * C1;    // 16,777,216
    short* w2p   = w1p + (size_t)3 * 9 * 8 * 512;        // 110,592
    short* zbuf  = w2p + (size_t)4 * 9 * 9 * 512;        // 165,888 (16B-aligned)

    const int tot1 = 3 * 9 * 8 * 512;                    // 110,592
    const int tot2 = 4 * 9 * 9 * 512;                    // 165,888

    transpose_feat<<<NN * HH, 256, 0, stream>>>(feat, featT, zbuf);
    pack_wB<<<(tot1 + 255) / 256, 256, 0, stream>>>(w1, w1p, CIN, 8, tot1);
    pack_wB<<<(tot2 + 255) / 256, 256, 0, stream>>>(w2, w2p, C1, 9, tot2);
    conv1_mfma<<<NN * HH, 256, 0, stream>>>(featT, w1p, b1, hfeat, zbuf);
    conv2_fused<<<NN * HH, 256, 0, stream>>>(hfeat, w2p, b2, flow, out, zbuf);
}

// Round 2
// 241.724 us; speedup vs baseline: 1.1114x; 1.1114x over previous
//
#include <hip/hip_runtime.h>
#include <hip/hip_bf16.h>

#define NN  4
#define CIN 96
#define C1  128
#define C2  144
#define HH  128
#define WW  256
#define NPX ((size_t)NN * HH * WW)          // pixels per chunk-plane (131072)

typedef short bf16x8 __attribute__((ext_vector_type(8)));
typedef float f32x4  __attribute__((ext_vector_type(4)));
typedef unsigned int u32x4 __attribute__((ext_vector_type(4)));

__device__ __forceinline__ short f2bs(float v) {
    __hip_bfloat16 b = __float2bfloat16(v);
    short s; __builtin_memcpy(&s, &b, 2); return s;
}

// async global->LDS, 16B per lane. LDS dest linear (base + lane*16).
__device__ __forceinline__ void gld16(const void* g, void* l) {
    __builtin_amdgcn_global_load_lds(
        (const __attribute__((address_space(1))) void*)g,
        (__attribute__((address_space(3))) void*)l, 16, 0, 0);
}

// ---------------------------------------------------------------------------
// NCHW fp32 -> chunk-major bf16: featT[kc][n][h][w][32], kc = ci>>5.
// Block = (n,h). LDS pair-packed (row stride 258 dwords, conflict-free).
// Store phase writes each chunk row as one contiguous 16KB stream.
__global__ __launch_bounds__(256) void transpose_feat(
    const float* __restrict__ feat, short* __restrict__ featT,
    short* __restrict__ zbuf)
{
    __shared__ unsigned int lds[48 * 258];        // 49.5 KB
    const int tid = threadIdx.x;
    const int h = blockIdx.x & (HH - 1);
    const int n = blockIdx.x >> 7;

    if (blockIdx.x == 0 && tid < 32) zbuf[tid] = 0;

    #pragma unroll 4
    for (int cp = 0; cp < 48; ++cp) {             // channel pairs
        float v0 = feat[(((size_t)n * CIN + 2 * cp    ) * HH + h) * WW + tid];
        float v1 = feat[(((size_t)n * CIN + 2 * cp + 1) * HH + h) * WW + tid];
        unsigned int p = (unsigned int)(unsigned short)f2bs(v0)
                       | ((unsigned int)(unsigned short)f2bs(v1) << 16);
        lds[cp * 258 + tid] = p;
    }
    __syncthreads();
    // chunk row = 256 px * 64B contiguous; slot -> (px = slot>>2, sub = slot&3)
    const size_t rowbase = (size_t)(n * HH + h) * WW * 32;
    #pragma unroll
    for (int kc = 0; kc < 3; ++kc) {
        short* dst = featT + (size_t)kc * (NPX * 32) + rowbase;
        #pragma unroll
        for (int it = 0; it < 4; ++it) {
            const int slot = it * 256 + tid;
            const int px = slot >> 2, sub = slot & 3;
            u32x4 v;                               // ci pairs kc*16+sub*4+k
            #pragma unroll
            for (int k = 0; k < 4; ++k)
                v[k] = lds[(kc * 16 + sub * 4 + k) * 258 + px];
            *(u32x4*)&dst[(size_t)slot * 8] = v;
        }
    }
}

// ---------------------------------------------------------------------------
// Pack weights (co,ci,3,3) fp32 -> B-fragment-ordered bf16:
// wp[(((kci*9+tap)*nct + ct)*64 + lane)*8 + j], co=ct*16+col, ci=kci*32+quad*8+j
__global__ __launch_bounds__(256) void pack_wB(
    const float* __restrict__ w, short* __restrict__ wp,
    int cin, int nct, int total)
{
    int i = blockIdx.x * 256 + threadIdx.x;
    if (i >= total) return;
    const int j    = i & 7;
    const int col  = (i >> 3) & 15;
    const int quad = (i >> 7) & 3;
    int t = i >> 9;                               // (kci*9+tap)*nct + ct
    const int ct  = t % nct;  t /= nct;
    const int tap = t % 9;
    const int kci = t / 9;
    const int co = ct * 16 + col;
    const int ci = kci * 32 + quad * 8 + j;
    wp[i] = f2bs(w[((size_t)co * cin + ci) * 9 + tap]);
}

// ---------------------------------------------------------------------------
// conv1: featT (chunk-major) -> hfeat (chunk-major). Block = (n,h), 256 thr /
// 4 waves, each wave a 64-px strip (mt=4). Staging slot = (row*258+px)*4+cig:
// global addresses fully contiguous per row (16.5KB streams), LDS layout
// [row][px][32ci] (b128 reads hit all 32 banks x8 = optimal).
__global__ __launch_bounds__(256, 2) void conv1_mfma(
    const short* __restrict__ featT, const short* __restrict__ w1p,
    const float* __restrict__ b1, short* __restrict__ hfeat,
    const short* __restrict__ zbuf)
{
    __shared__ __attribute__((aligned(16))) short lds[3 * 258 * 32]; // 49,536 B
    const int tid  = threadIdx.x;
    const int h    = blockIdx.x & (HH - 1);
    const int n    = blockIdx.x >> 7;
    const int lane = tid & 63, wave = tid >> 6;
    const int quad = lane >> 4, col = lane & 15;
    const int wp0  = wave * 64;

    f32x4 acc[4][8];
    #pragma unroll
    for (int mt = 0; mt < 4; ++mt)
        #pragma unroll
        for (int ct = 0; ct < 8; ++ct)
            #pragma unroll
            for (int r = 0; r < 4; ++r) acc[mt][ct][r] = 0.f;

    for (int kci = 0; kci < 3; ++kci) {
        if (kci) __syncthreads();
        const short* cbase = featT + (size_t)kci * (NPX * 32);
        for (int s = tid; s < 3 * 258 * 4; s += 256) {
            const int cig = s & 3;
            const int px  = (s >> 2) % 258;
            const int row = (s >> 2) / 258;
            const int hh = h + row - 1, gw = px - 1;
            const short* g = zbuf;
            if (hh >= 0 && hh < HH && gw >= 0 && gw < WW)
                g = cbase + ((size_t)(n * HH + hh) * WW + gw) * 32 + cig * 8;
            gld16(g, &lds[s * 8]);
        }
        __syncthreads();
        #pragma unroll
        for (int tap = 0; tap < 9; ++tap) {
            const int dh = tap / 3, dw = tap % 3;
            bf16x8 af[4];
            #pragma unroll
            for (int mt = 0; mt < 4; ++mt)
                af[mt] = *(const bf16x8*)
                    &lds[(dh * 258 + wp0 + mt * 16 + col + dw) * 32 + quad * 8];
            const short* bp = w1p + (((size_t)(kci * 9 + tap) * 8) << 9) + (lane << 3);
            #pragma unroll
            for (int ct = 0; ct < 8; ++ct) {
                const bf16x8 bfr = *(const bf16x8*)(bp + ((size_t)ct << 9));
                #pragma unroll
                for (int mt = 0; mt < 4; ++mt)
                    acc[mt][ct] = __builtin_amdgcn_mfma_f32_16x16x32_bf16(af[mt], bfr, acc[mt][ct], 0, 0, 0);
            }
        }
    }

    float bias[8];
    #pragma unroll
    for (int ct = 0; ct < 8; ++ct) bias[ct] = b1[ct * 16 + col];
    #pragma unroll
    for (int mt = 0; mt < 4; ++mt)
        #pragma unroll
        for (int r = 0; r < 4; ++r) {
            const int w = wp0 + mt * 16 + quad * 4 + r;
            const size_t pxw = (size_t)(n * HH + h) * WW + w;
            #pragma unroll
            for (int ct = 0; ct < 8; ++ct) {
                float a = acc[mt][ct][r] + bias[ct];
                a = a > 0.f ? a : 0.1f * a;       // LeakyReLU(0.1)
                // chunk-major: kc = ct>>1, within-chunk ch = (ct&1)*16+col
                hfeat[((size_t)(ct >> 1) * NPX + pxw) * 32 + (ct & 1) * 16 + col] = f2bs(a);
            }
        }
}

// ---------------------------------------------------------------------------
// conv2 + fused bias/0.25/softmax-9/convex-upsample. Same staged structure,
// hfeat chunk-major, K = 128 in 4 chunks. Lane col=ab keeps all 9 logits.
__global__ __launch_bounds__(256, 2) void conv2_fused(
    const short* __restrict__ hfeat, const short* __restrict__ w2p,
    const float* __restrict__ b2, const float* __restrict__ flow,
    float* __restrict__ out, const short* __restrict__ zbuf)
{
    __shared__ __attribute__((aligned(16))) short lds[3 * 258 * 32]; // 49,536 B
    __shared__ float flds[2 * 3 * 264];                               // 6,336 B
    const int tid  = threadIdx.x;
    const int h    = blockIdx.x & (HH - 1);
    const int n    = blockIdx.x >> 7;
    const int lane = tid & 63, wave = tid >> 6;
    const int quad = lane >> 4, col = lane & 15;
    const int wp0  = wave * 64;

    // stage flow rows h-1..h+1 (zero-padded); later barriers order it
    for (int i = tid; i < 2 * 3 * 258; i += 256) {
        const int px = i % 258;
        const int t  = i / 258;
        const int row = t % 3, c = t / 3;
        const int hh = h + row - 1, gw = px - 1;
        float v = 0.f;
        if (hh >= 0 && hh < HH && gw >= 0 && gw < WW)
            v = flow[(((size_t)n * 2 + c) * HH + hh) * WW + gw];
        flds[(c * 3 + row) * 264 + px] = v;
    }

    f32x4 acc[4][9];
    #pragma unroll
    for (int mt = 0; mt < 4; ++mt)
        #pragma unroll
        for (int ct = 0; ct < 9; ++ct)
            #pragma unroll
            for (int r = 0; r < 4; ++r) acc[mt][ct][r] = 0.f;

    for (int kci = 0; kci < 4; ++kci) {
        if (kci) __syncthreads();
        const short* cbase = hfeat + (size_t)kci * (NPX * 32);
        for (int s = tid; s < 3 * 258 * 4; s += 256) {
            const int cig = s & 3;
            const int px  = (s >> 2) % 258;
            const int row = (s >> 2) / 258;
            const int hh = h + row - 1, gw = px - 1;
            const short* g = zbuf;
            if (hh >= 0 && hh < HH && gw >= 0 && gw < WW)
                g = cbase + ((size_t)(n * HH + hh) * WW + gw) * 32 + cig * 8;
            gld16(g, &lds[s * 8]);
        }
        __syncthreads();
        #pragma unroll
        for (int tap = 0; tap < 9; ++tap) {
            const int dh = tap / 3, dw = tap % 3;
            bf16x8 af[4];
            #pragma unroll
            for (int mt = 0; mt < 4; ++mt)
                af[mt] = *(const bf16x8*)
                    &lds[(dh * 258 + wp0 + mt * 16 + col + dw) * 32 + quad * 8];
            const short* bp = w2p + (((size_t)(kci * 9 + tap) * 9) << 9) + (lane << 3);
            #pragma unroll
            for (int ct = 0; ct < 9; ++ct) {
                const bf16x8 bfr = *(const bf16x8*)(bp + ((size_t)ct << 9));
                #pragma unroll
                for (int mt = 0; mt < 4; ++mt)
                    acc[mt][ct] = __builtin_amdgcn_mfma_f32_16x16x32_bf16(af[mt], bfr, acc[mt][ct], 0, 0, 0);
            }
        }
    }

    const int a_ = col >> 2, b_ = col & 3;
    float bias[9];
    #pragma unroll
    for (int k = 0; k < 9; ++k) bias[k] = b2[k * 16 + col];
    const int H4 = 4 * HH, W4 = 4 * WW;

    #pragma unroll
    for (int mt = 0; mt < 4; ++mt) {
        const int w0 = wp0 + mt * 16 + quad * 4;
        float fw[2][3][6];                        // flow window w0-1 .. w0+4
        #pragma unroll
        for (int c = 0; c < 2; ++c)
            #pragma unroll
            for (int ki = 0; ki < 3; ++ki)
                #pragma unroll
                for (int j = 0; j < 6; ++j)
                    fw[c][ki][j] = flds[(c * 3 + ki) * 264 + w0 + j];
        #pragma unroll
        for (int r = 0; r < 4; ++r) {
            const int w = w0 + r;
            float v[9], mx = -1e30f;
            #pragma unroll
            for (int k = 0; k < 9; ++k) {
                v[k] = 0.25f * (acc[mt][k][r] + bias[k]);
                mx = fmaxf(mx, v[k]);
            }
            float s = 0.f;
            #pragma unroll
            for (int k = 0; k < 9; ++k) { v[k] = __expf(v[k] - mx); s += v[k]; }
            const float inv = 4.f / s;            // folds the 4*flow scale
            float o0 = 0.f, o1 = 0.f;
            #pragma unroll
            for (int ki = 0; ki < 3; ++ki)
                #pragma unroll
                for (int kj = 0; kj < 3; ++kj) {
                    const float wgt = v[ki * 3 + kj];
                    o0 += wgt * fw[0][ki][r + kj];
                    o1 += wgt * fw[1][ki][r + kj];
                }
            const size_t o = ((size_t)(n * 2) * H4 + 4 * h + a_) * W4 + 4 * w + b_;
            out[o] = o0 * inv;
            out[o + (size_t)H4 * W4] = o1 * inv;
        }
    }
}

// ---------------------------------------------------------------------------
extern "C" void kernel_launch(void* const* d_in, const int* in_sizes, int n_in,
                              void* d_out, int out_size, void* d_ws, size_t ws_size,
                              hipStream_t stream)
{
    const float* flow = (const float*)d_in[0];
    const float* feat = (const float*)d_in[1];
    const float* w1   = (const float*)d_in[2];
    const float* b1   = (const float*)d_in[3];
    const float* w2   = (const float*)d_in[4];
    const float* b2   = (const float*)d_in[5];
    float* out = (float*)d_out;

    // ws: featT 25.2 MB + hfeat 33.6 MB + w1p 0.22 MB + w2p 0.33 MB + zbuf 64B
    short* featT = (short*)d_ws;
    short* hfeat = featT + (size_t)3 * NPX * 32;         // 12,582,912
    short* w1p   = hfeat + (size_t)4 * NPX * 32;         // 16,777,216
    short* w2p   = w1p + (size_t)3 * 9 * 8 * 512;        // 110,592
    short* zbuf  = w2p + (size_t)4 * 9 * 9 * 512;        // 165,888 (16B-aligned)

    const int tot1 = 3 * 9 * 8 * 512;                    // 110,592
    const int tot2 = 4 * 9 * 9 * 512;                    // 165,888

    transpose_feat<<<NN * HH, 256, 0, stream>>>(feat, featT, zbuf);
    pack_wB<<<(tot1 + 255) / 256, 256, 0, stream>>>(w1, w1p, CIN, 8, tot1);
    pack_wB<<<(tot2 + 255) / 256, 256, 0, stream>>>(w2, w2p, C1, 9, tot2);
    conv1_mfma<<<NN * HH, 256, 0, stream>>>(featT, w1p, b1, hfeat, zbuf);
    conv2_fused<<<NN * HH, 256, 0, stream>>>(hfeat, w2p, b2, flow, out, zbuf);
}